// Round 2
// baseline (54.841 us; speedup 1.0000x reference)
//
#include <hip/hip_runtime.h>

// Problem constants (fixed by the reference setup)
constexpr int Mdim = 2048;
constexpr int Kdim = 1024;
constexpr int Ndim = 1024;
constexpr int Gdim = 64;
constexpr int ROWS = 32;   // rows per group tile (M/G)

typedef float          f32x16 __attribute__((ext_vector_type(16)));
typedef __bf16         bf16x8 __attribute__((ext_vector_type(8)));
typedef unsigned short u16x4  __attribute__((ext_vector_type(4)));
typedef unsigned short u16x8  __attribute__((ext_vector_type(8)));

static __device__ __forceinline__ unsigned short f2bf_rne(float f) {
  unsigned u = __float_as_uint(f);
  u += 0x7FFFu + ((u >> 16) & 1u);
  return (unsigned short)(u >> 16);
}

// out[m,n] = scale[g,n] * ( sum_k x[m,k]*w[g,k,n] + off[g,n] * sum_k x[m,k] )
// Grid: G*4 blocks of 512 threads (8 waves). Block b -> group g=b>>2, n-range (b&3)*256.
// Wave w owns a 32x32 output tile at n0 = (b&3)*256 + w*32.
// x group-tile staged once in LDS as bf16 (XOR-swizzled); weights loaded
// direct-to-register (B-fragment native layout); rowsum via MFMA vs ones.
__global__ __launch_bounds__(512)
void gmm_wq_kernel(const float* __restrict__ x,
                   const int*   __restrict__ w,
                   const float* __restrict__ scale,
                   const float* __restrict__ offs,
                   const void*  __restrict__ gl_raw,
                   const int*   __restrict__ glt,
                   float*       __restrict__ out)
{
  __shared__ __align__(16) unsigned short xs[ROWS * Kdim]; // 64 KB bf16, swizzled

  const int tid   = threadIdx.x;
  const int blk   = blockIdx.x;
  const int g     = blk >> 2;
  const int nbase = (blk & 3) << 8;

  // ---- group extent from group_list (handles int32/int64, type 0/1) ----
  const int*       gl32 = (const int*)gl_raw;
  const long long* gl64 = (const long long*)gl_raw;
  const bool is64 = (gl32[1] == 0);   // int64 LE: high word of entry 0 is 0
  auto glv = [&](int i) -> long long { return is64 ? gl64[i] : (long long)gl32[i]; };
  int row_start, rows;
  if (glt[0] == 0) {                   // cumulative
    long long prev = (g == 0) ? 0 : glv(g - 1);
    row_start = (int)prev;
    rows      = (int)(glv(g) - prev);
  } else {                             // per-group counts
    long long s = 0;
    for (int i = 0; i < g; ++i) s += glv(i);
    row_start = (int)s;
    rows      = (int)glv(g);
  }
  rows = (rows > ROWS) ? ROWS : rows;

  // ---- stage x group tile -> LDS bf16, XOR-swizzled ((row&7)<<4 on byte addr) ----
  {
    const int r   = tid >> 4;          // 0..31, one row per 16 threads
    const int c16 = tid & 15;
    const bool valid = (r < rows);
    const float4* xr = (const float4*)(x + (size_t)(row_start + r) * Kdim);
    const int swz = (r & 7) << 4;
    char* base = (char*)xs + r * (Kdim * 2);
    #pragma unroll
    for (int it = 0; it < 16; ++it) {
      const int c4 = c16 + it * 16;    // float4 index 0..255
      float4 v = make_float4(0.f, 0.f, 0.f, 0.f);
      if (valid) v = xr[c4];
      u16x4 h;
      h.x = f2bf_rne(v.x); h.y = f2bf_rne(v.y);
      h.z = f2bf_rne(v.z); h.w = f2bf_rne(v.w);
      *(u16x4*)(base + ((c4 * 8) ^ swz)) = h;
    }
  }
  __syncthreads();

  // ---- per-wave GEMM: 32 rows x 32 cols, K-loop of 64 steps (K=16 each) ----
  const int lane  = tid & 63;
  const int wave  = tid >> 6;
  const int n0    = nbase + wave * 32;
  const int nlane = lane & 31;
  const int khalf = lane >> 5;         // 0/1: k-offset 0/8 for A,B frags; row-offset 0/4 for C/D

  const int* wg   = w + (size_t)g * Kdim * Ndim;      // uniform base
  // FIX (R1): column must include the wave's n-tile base n0, not just lane&31.
  const int  voff = n0 + nlane + khalf * 8 * Ndim;    // divergent 32-bit offset

  const int abase = nlane * (Kdim * 2) + khalf * 16;  // A row = lane&31
  const int axor  = (nlane & 7) << 4;
  const char* xsb = (const char*)xs;

  f32x16 acc, rs;
  #pragma unroll
  for (int i = 0; i < 16; ++i) { acc[i] = 0.f; rs[i] = 0.f; }
  bf16x8 ones;
  #pragma unroll
  for (int e = 0; e < 8; ++e) ones[e] = (__bf16)1.0f;

  auto loadW = [&](int kk, int (&d)[8]) {
    const int* p = wg + (size_t)(kk * 16) * Ndim + voff;
    #pragma unroll
    for (int e = 0; e < 8; ++e) d[e] = p[(size_t)e * Ndim];
  };
  auto cvtW = [&](const int (&s)[8]) -> bf16x8 {
    u16x8 r;
    #pragma unroll
    for (int e = 0; e < 8; ++e)   // exact for |w|<=8: low16 of f32 is zero
      r[e] = (unsigned short)(__float_as_uint((float)s[e]) >> 16);
    return __builtin_bit_cast(bf16x8, r);
  };
  auto ldsA = [&](int kk) -> bf16x8 {
    return *(const bf16x8*)(xsb + ((abase + kk * 32) ^ axor));
  };

  int Wa[8], Wb[8], Wc[8];
  loadW(0, Wa); loadW(1, Wb); loadW(2, Wc);

  for (int kk = 0; kk < 63; kk += 3) {
    {
      bf16x8 b = cvtW(Wa);
      if (kk + 3 < 64) loadW(kk + 3, Wa);
      bf16x8 a = ldsA(kk);
      acc = __builtin_amdgcn_mfma_f32_32x32x16_bf16(a, b,    acc, 0, 0, 0);
      rs  = __builtin_amdgcn_mfma_f32_32x32x16_bf16(a, ones, rs,  0, 0, 0);
    }
    {
      bf16x8 b = cvtW(Wb);
      if (kk + 4 < 64) loadW(kk + 4, Wb);
      bf16x8 a = ldsA(kk + 1);
      acc = __builtin_amdgcn_mfma_f32_32x32x16_bf16(a, b,    acc, 0, 0, 0);
      rs  = __builtin_amdgcn_mfma_f32_32x32x16_bf16(a, ones, rs,  0, 0, 0);
    }
    {
      bf16x8 b = cvtW(Wc);
      if (kk + 5 < 64) loadW(kk + 5, Wc);
      bf16x8 a = ldsA(kk + 2);
      acc = __builtin_amdgcn_mfma_f32_32x32x16_bf16(a, b,    acc, 0, 0, 0);
      rs  = __builtin_amdgcn_mfma_f32_32x32x16_bf16(a, ones, rs,  0, 0, 0);
    }
  }
  { // tail step 63 (held in Wa)
    bf16x8 b = cvtW(Wa);
    bf16x8 a = ldsA(63);
    acc = __builtin_amdgcn_mfma_f32_32x32x16_bf16(a, b,    acc, 0, 0, 0);
    rs  = __builtin_amdgcn_mfma_f32_32x32x16_bf16(a, ones, rs,  0, 0, 0);
  }

  // ---- epilogue: C/D layout col=lane&31, row=(r&3)+8*(r>>2)+4*(lane>>5) ----
  const int col = n0 + nlane;
  const float sc = scale[g * Ndim + col];
  const float of = offs [g * Ndim + col];
  #pragma unroll
  for (int r = 0; r < 16; ++r) {
    const int rl = (r & 3) + 8 * (r >> 2) + 4 * khalf;
    if (rl < rows)
      out[(size_t)(row_start + rl) * Ndim + col] = sc * (acc[r] + of * rs[r]);
  }
}

extern "C" void kernel_launch(void* const* d_in, const int* in_sizes, int n_in,
                              void* d_out, int out_size, void* d_ws, size_t ws_size,
                              hipStream_t stream) {
  const float* x   = (const float*)d_in[0];
  const int*   w   = (const int*)d_in[1];
  const float* sc  = (const float*)d_in[2];
  const float* of  = (const float*)d_in[3];
  const void*  gl  = d_in[4];
  const int*   glt = (const int*)d_in[5];
  float*       out = (float*)d_out;

  hipLaunchKernelGGL(gmm_wq_kernel, dim3(Gdim * 4), dim3(512), 0, stream,
                     x, w, sc, of, gl, glt, out);
}

// Round 3
// 54.654 us; speedup vs baseline: 1.0034x; 1.0034x over previous
//
#include <hip/hip_runtime.h>

// Problem constants (fixed by the reference setup)
constexpr int Kdim = 1024;
constexpr int Ndim = 1024;
constexpr int Gdim = 64;
constexpr int ROWS = 32;                       // rows per group (M/G)
constexpr size_t KSTEP_BYTES = 16ull * Ndim * 4; // 64 KB of weights per K=16 step

typedef float          f32x16 __attribute__((ext_vector_type(16)));
typedef __bf16         bf16x8 __attribute__((ext_vector_type(8)));
typedef unsigned short u16x4  __attribute__((ext_vector_type(4)));
typedef unsigned short u16x8  __attribute__((ext_vector_type(8)));

static __device__ __forceinline__ unsigned short f2bf_rne(float f) {
  unsigned u = __float_as_uint(f);
  u += 0x7FFFu + ((u >> 16) & 1u);
  return (unsigned short)(u >> 16);
}

// out[m,n] = scale[g,n] * ( sum_k x[m,k]*w[g,k,n] + off[g,n] * sum_k x[m,k] )
// Grid: 256 blocks x 512 threads (8 waves); block -> (group, n-quadrant) with
// XCD co-location (b&7 = assumed XCD; 8 whole groups per XCD so the 4
// quadrant-blocks of a group share one L2 for the x tile).
// Wave w owns a 32x32 output tile. x staged once in LDS (bf16, XOR-swizzled);
// weights direct-to-register (native B-fragment layout, uniform base +
// per-lane 32-bit voffset); rowsum precomputed during staging (no rs MFMA).
__global__ __launch_bounds__(512)
void gmm_wq_kernel(const float* __restrict__ x,
                   const int*   __restrict__ w,
                   const float* __restrict__ scale,
                   const float* __restrict__ offs,
                   const void*  __restrict__ gl_raw,
                   const int*   __restrict__ glt,
                   float*       __restrict__ out)
{
  __shared__ __align__(16) unsigned short xs[ROWS * Kdim]; // 64 KB bf16, swizzled
  __shared__ float xsum[ROWS];

  const int tid  = threadIdx.x;
  const int b    = blockIdx.x;
  const int slot = b >> 3;
  const int g     = (b & 7) * 8 + (slot >> 2);  // 8 groups per assumed-XCD
  const int nbase = (slot & 3) << 8;            // n-quadrant * 256

  // ---- group extent from group_list (handles int32/int64, type 0/1) ----
  const int*       gl32 = (const int*)gl_raw;
  const long long* gl64 = (const long long*)gl_raw;
  const bool is64 = (gl32[1] == 0);   // int64 LE: high word of entry 0 is 0
  auto glv = [&](int i) -> long long { return is64 ? gl64[i] : (long long)gl32[i]; };
  int row_start, rows;
  if (glt[0] == 0) {                   // cumulative
    long long prev = (g == 0) ? 0 : glv(g - 1);
    row_start = (int)prev;
    rows      = (int)(glv(g) - prev);
  } else {                             // per-group counts
    long long s = 0;
    for (int i = 0; i < g; ++i) s += glv(i);
    row_start = (int)s;
    rows      = (int)glv(g);
  }
  rows = (rows > ROWS) ? ROWS : rows;

  // ---- stage x tile -> LDS bf16 (XOR-swizzled) + per-row sums ----
  {
    const int r   = tid >> 4;          // 0..31, one row per 16 threads
    const int c16 = tid & 15;
    const bool valid = (r < rows);
    const float4* xr = (const float4*)(x + (size_t)(row_start + r) * Kdim);
    const int swz = (r & 7) << 4;
    char* base = (char*)xs + r * (Kdim * 2);
    float psum = 0.f;
    #pragma unroll
    for (int it = 0; it < 16; ++it) {
      const int c4 = c16 + it * 16;    // float4 index 0..255
      float4 v = make_float4(0.f, 0.f, 0.f, 0.f);
      if (valid) v = xr[c4];
      u16x4 h;
      h.x = f2bf_rne(v.x); h.y = f2bf_rne(v.y);
      h.z = f2bf_rne(v.z); h.w = f2bf_rne(v.w);
      *(u16x4*)(base + ((c4 * 8) ^ swz)) = h;
      psum += __uint_as_float((unsigned)h.x << 16)
            + __uint_as_float((unsigned)h.y << 16)
            + __uint_as_float((unsigned)h.z << 16)
            + __uint_as_float((unsigned)h.w << 16);
    }
    #pragma unroll
    for (int m = 8; m >= 1; m >>= 1) psum += __shfl_xor(psum, m);
    if (c16 == 0) xsum[r] = psum;      // rowsum of bf16-rounded x
  }
  __syncthreads();

  // ---- per-wave GEMM: 32 rows x 32 cols, 64 K-steps of K=16 ----
  const int lane  = tid & 63;
  const int wave  = tid >> 6;
  const int n0    = nbase + wave * 32;
  const int nlane = lane & 31;
  const int khalf = lane >> 5;

  // Uniform weight base (advanced per K-step) + per-lane 32-bit byte offsets.
  const char* wbase = (const char*)w + (size_t)g * Kdim * Ndim * 4;
  int woff[8];
  #pragma unroll
  for (int e = 0; e < 8; ++e)
    woff[e] = ((khalf * 8 + e) * Ndim + n0 + nlane) * 4;

  const int abase = nlane * (Kdim * 2) + khalf * 16;  // A row = lane&31
  const int axor  = (nlane & 7) << 4;
  const char* xsb = (const char*)xs;

  f32x16 acc;
  #pragma unroll
  for (int i = 0; i < 16; ++i) acc[i] = 0.f;

  auto loadW = [&](const char* p, int (&d)[8]) {
    #pragma unroll
    for (int e = 0; e < 8; ++e) d[e] = *(const int*)(p + woff[e]);
  };
  auto cvtW = [&](const int (&s)[8]) -> bf16x8 {
    u16x8 r;
    #pragma unroll
    for (int e = 0; e < 8; ++e)   // exact for |w|<=8: low16 of f32 is zero
      r[e] = (unsigned short)(__float_as_uint((float)s[e]) >> 16);
    return __builtin_bit_cast(bf16x8, r);
  };
  auto ldsA = [&](int kk) -> bf16x8 {
    return *(const bf16x8*)(xsb + ((abase + kk * 32) ^ axor));
  };

  int Wa[8], Wb[8], Wc[8];
  loadW(wbase,                   Wa);
  loadW(wbase +     KSTEP_BYTES, Wb);
  loadW(wbase + 2 * KSTEP_BYTES, Wc);

  for (int kk = 0; kk < 63; kk += 3) {
    const char* pf = wbase + (size_t)(kk + 3) * KSTEP_BYTES;
    {
      bf16x8 bfr = cvtW(Wa);
      if (kk + 3 < 64) loadW(pf, Wa);
      acc = __builtin_amdgcn_mfma_f32_32x32x16_bf16(ldsA(kk), bfr, acc, 0, 0, 0);
    }
    {
      bf16x8 bfr = cvtW(Wb);
      if (kk + 4 < 64) loadW(pf + KSTEP_BYTES, Wb);
      acc = __builtin_amdgcn_mfma_f32_32x32x16_bf16(ldsA(kk + 1), bfr, acc, 0, 0, 0);
    }
    {
      bf16x8 bfr = cvtW(Wc);
      if (kk + 5 < 64) loadW(pf + 2 * KSTEP_BYTES, Wc);
      acc = __builtin_amdgcn_mfma_f32_32x32x16_bf16(ldsA(kk + 2), bfr, acc, 0, 0, 0);
    }
  }
  { // tail step 63 (held in Wa)
    bf16x8 bfr = cvtW(Wa);
    acc = __builtin_amdgcn_mfma_f32_32x32x16_bf16(ldsA(63), bfr, acc, 0, 0, 0);
  }

  // ---- epilogue: C/D layout col=lane&31, row=(r&3)+8*(r>>2)+4*(lane>>5) ----
  const int col = n0 + nlane;
  const float sc = scale[g * Ndim + col];
  const float of = offs [g * Ndim + col];
  #pragma unroll
  for (int r = 0; r < 16; ++r) {
    const int rl = (r & 3) + 8 * (r >> 2) + 4 * khalf;
    if (rl < rows)
      out[(size_t)(row_start + rl) * Ndim + col] = sc * (acc[r] + of * xsum[rl]);
  }
}

extern "C" void kernel_launch(void* const* d_in, const int* in_sizes, int n_in,
                              void* d_out, int out_size, void* d_ws, size_t ws_size,
                              hipStream_t stream) {
  const float* x   = (const float*)d_in[0];
  const int*   w   = (const int*)d_in[1];
  const float* sc  = (const float*)d_in[2];
  const float* of  = (const float*)d_in[3];
  const void*  gl  = d_in[4];
  const int*   glt = (const int*)d_in[5];
  float*       out = (float*)d_out;

  hipLaunchKernelGGL(gmm_wq_kernel, dim3(Gdim * 4), dim3(512), 0, stream,
                     x, w, sc, of, gl, glt, out);
}